// Round 12
// baseline (223.202 us; speedup 1.0000x reference)
//
#include <hip/hip_runtime.h>
#include <math.h>

#define N_BATCH 8
#define IN_CH   256
#define OUT_CH  256
#define T_LEN   2048
#define DKS     33
#define PAD     16
#define KC      16

// conv tiling: block 128o x 128t, 4 waves in 2x2 grid, wave tile 64o x 64t.
#define TT 128
#define XS_STRIDE 40   // Xs row stride in bf16 elements (80B, 16B-aligned)

typedef __attribute__((ext_vector_type(8))) short bf16x8;
typedef __attribute__((ext_vector_type(4))) float f32x4;

typedef const __attribute__((address_space(1))) unsigned int glb_uint;
typedef __attribute__((address_space(3))) unsigned int lds_uint;

__device__ __forceinline__ unsigned short f2bf(float f) {
    unsigned u = __builtin_bit_cast(unsigned, f);
    unsigned r = (u + 0x7FFFu + ((u >> 16) & 1u)) >> 16;   // RNE
    return (unsigned short)r;
}

// ---------------------------------------------------------------------------
// Kernel 1: construct dense conv kernel in bf16, fragment-ready layout:
//   element (o,i,d) lives at
//   ((g*8 + c)*33 + d)*2048 + a*512 + l*8 + j
//   where g=o>>6, a=(o>>4)&3, m=o&15, c=i>>5, i_local=i&31,
//         quad=i_local>>3, j=i_local&7, l=quad*16+m.
// GATHER formulation (no runtime-indexed array -> no scratch).
// Faithful reference semantics: frac from out-channel 0; second tap dropped
// when p1+1 == 33 (d-1 <= 31 never matches).
// ---------------------------------------------------------------------------
__global__ void build_kern(const float* __restrict__ weight,
                           const float* __restrict__ P,
                           unsigned short* __restrict__ kern_f) {
    int idx = blockIdx.x * blockDim.x + threadIdx.x;   // o*IN_CH + i
    if (idx >= OUT_CH * IN_CH) return;
    int o = idx / IN_CH;
    int i = idx % IN_CH;

    const float* Po = P      + (size_t)(o * IN_CH + i) * KC;
    const float* P0 = P      + (size_t)i * KC;           // out-channel 0
    const float* Wo = weight + (size_t)(o * IN_CH + i) * KC;

    int   p1[KC];
    float w1[KC], w2[KC];
#pragma unroll
    for (int k = 0; k < KC; ++k) {
        float pp = Po[k] + (float)(DKS / 2);
        float p0 = P0[k] + (float)(DKS / 2);
        float fr = p0 - floorf(p0);
        float w  = Wo[k];
        p1[k] = (int)floorf(pp);
        w1[k] = w * (1.0f - fr);
        w2[k] = w * fr;
    }

    int g  = o >> 6;
    int ai = (o >> 4) & 3;
    int m  = o & 15;
    int c  = i >> 5;
    int il = i & 31;
    int q  = il >> 3;
    int j  = il & 7;
    size_t base = ((size_t)(g * 8 + c) * 33) * 2048
                + (size_t)ai * 512 + (size_t)(q * 16 + m) * 8 + j;

#pragma unroll
    for (int d = 0; d < DKS; ++d) {
        float acc = 0.0f;
#pragma unroll
        for (int k = 0; k < KC; ++k) {
            acc += (p1[k] == d)     ? w1[k] : 0.0f;
            acc += (p1[k] == d - 1) ? w2[k] : 0.0f;
        }
        kern_f[base + (size_t)d * 2048] = f2bf(acc);
    }
}

// ---------------------------------------------------------------------------
// Kernel 2: implicit-GEMM conv with MFMA 16x16x32 bf16.
// r11 post-mortem: LDS read pipe was ~100% busy (reads/MFMA = 1 with 2x
// fragment reuse) -- the conserved wall across r1..r11. Fix: square 64x64
// wave tiles -> 4x reuse on BOTH operands -> reads/MFMA = 0.5 -> LDS ~55%.
// Block 128o x 128t = 4 waves (2x2); grid (16,2,8) = 256 blocks = 1/CU.
// Occupancy ~12% is EXPECTED: per-phase MFMA work (16/wave) self-hides
// ds_read latency; A global latency hidden by the r11-proven counted-vmcnt
// gload_lds pipeline (4 bufs x 8KB, stage d+2, VMW before BAR, never 0
// mid-loop). 33 single-d phases per chunk, no tail.
// ---------------------------------------------------------------------------
__global__ __launch_bounds__(256) void dcls_conv(
    const float* __restrict__ x,
    const unsigned short* __restrict__ kern_f,
    const float* __restrict__ bias,
    float* __restrict__ out)
{
    __shared__ unsigned short Xs[(TT + 2 * PAD) * XS_STRIDE];       // 12.8 KB
    __shared__ __align__(16) unsigned short Abuf[4][2][4][512];     // 32 KB

    const int t0    = blockIdx.x * TT;        // t-block (16)
    const int o0    = blockIdx.y * 128;       // o-block (2)
    const int batch = blockIdx.z;

    const int tid  = threadIdx.x;
    const int w    = tid >> 6;        // wave id 0..3
    const int l    = tid & 63;
    const int quad = l >> 4;
    const int lm   = l & 15;
    const int wo   = w >> 1;          // wave o-half: g' in {0,1}
    const int wt   = (w & 1) * 64;    // wave t-base (local)

    f32x4 acc[4][4];
#pragma unroll
    for (int a = 0; a < 4; ++a)
#pragma unroll
        for (int b = 0; b < 4; ++b) acc[a][b] = (f32x4){0.f, 0.f, 0.f, 0.f};

    // wave's staging share of each 8KB d-slab: g' = w>>1, a-rows (w&1)*2 +{0,1}
    const int sg = w >> 1;
    const int sa = (w & 1) * 2;

#define VMW(N) asm volatile("s_waitcnt vmcnt(" #N ")" ::: "memory")
#define BAR()  asm volatile("s_barrier" ::: "memory")

    // stage d-slab D into Abuf[NB]: 2 x 1KB gload_lds per wave (8KB total).
    // kwb = per-wave kern base for this chunk (includes g_global = by*2+sg).
#define STAGE_A(D, NB)                                                        \
    do {                                                                      \
        _Pragma("unroll")                                                     \
        for (int j_ = 0; j_ < 2; ++j_) {                                      \
            const unsigned short* s_ = kern_f + kwb                           \
                + (size_t)(D) * 2048 + (size_t)(sa + j_) * 512                \
                + (size_t)l * 8;                                              \
            __builtin_amdgcn_global_load_lds((glb_uint*)s_,                   \
                (lds_uint*)&Abuf[NB][sg][sa + j_][0], 16, 0, 0);              \
        }                                                                     \
    } while (0)

    // one phase: A-frags (4) of wave's o-half + B-frags (4), 16 MFMA
#define PHASE_BODY(NB, D)                                                     \
    do {                                                                      \
        bf16x8 afr[4], bfr[4];                                                \
        _Pragma("unroll")                                                     \
        for (int a = 0; a < 4; ++a)                                           \
            afr[a] = *(const bf16x8*)(&Abuf[NB][wo][a][(size_t)l * 8]);       \
        _Pragma("unroll")                                                     \
        for (int b = 0; b < 4; ++b)                                           \
            bfr[b] = *(const bf16x8*)(&Xs[(wt + b * 16 + lm + (D)) * XS_STRIDE + quad * 8]); \
        __builtin_amdgcn_s_setprio(1);                                        \
        _Pragma("unroll")                                                     \
        for (int a = 0; a < 4; ++a)                                           \
            _Pragma("unroll")                                                 \
            for (int b = 0; b < 4; ++b)                                       \
                acc[a][b] = __builtin_amdgcn_mfma_f32_16x16x32_bf16(          \
                    afr[a], bfr[b], acc[a][b], 0, 0, 0);                      \
        __builtin_amdgcn_s_setprio(0);                                        \
    } while (0)

    for (int c = 0; c < 8; ++c) {
        __syncthreads();   // prev chunk's Xs/Abuf reads done; vmcnt drained

        const size_t kwb = ((size_t)((blockIdx.y * 2 + sg) * 8 + c) * 33) * 2048;

        // prologue: 2-deep A prefetch (d=0,1 -> bufs 0,1)
        STAGE_A(0, 0);
        STAGE_A(1, 1);

        // ---- stage Xs: 32 i x 160 t, transposed, fp32 -> bf16 (RNE) ----
        const int i0 = c * 32;
#pragma unroll
        for (int it = 0; it < 10; ++it) {
            int idx = tid + it * 256;          // 0..2559
            int ip  = idx / 160;               // i-pair 0..15
            int t   = idx - ip * 160;          // 0..159
            int gg  = t0 - PAD + t;
            float v0 = 0.f, v1 = 0.f;
            if ((unsigned)gg < (unsigned)T_LEN) {
                const float* xb = x + ((size_t)(batch * IN_CH + i0 + ip * 2) * T_LEN) + gg;
                v0 = xb[0];
                v1 = xb[T_LEN];
            }
            unsigned pk = (unsigned)f2bf(v0) | ((unsigned)f2bf(v1) << 16);
            *(unsigned*)(&Xs[t * XS_STRIDE + ip * 2]) = pk;
        }
        __syncthreads();   // Xs ready; prologue A-stages landed (full drain)

        // ---- 33 single-d phases, counted-vmcnt pipeline (never 0 mid-loop) ----
        for (int p = 0; p < 31; ++p) {
            STAGE_A(p + 2, (p + 2) & 3);   // stage phase p+2 (2 loads)
            VMW(4);    // phase p's 2 loads landed; p+1,p+2 (4) in flight
            BAR();     // all waves arrived => full 8KB buf[p&3] resident
            PHASE_BODY(p & 3, p);
        }
        VMW(2); BAR(); PHASE_BODY(3, 31);   // p=31
        VMW(0); BAR(); PHASE_BODY(0, 32);   // p=32
    }
#undef STAGE_A
#undef PHASE_BODY
#undef VMW
#undef BAR

    // ---- epilogue: bias + fp32 stores ----
#pragma unroll
    for (int a = 0; a < 4; ++a) {
#pragma unroll
        for (int r = 0; r < 4; ++r) {
            int o = o0 + wo * 64 + a * 16 + quad * 4 + r;
            float bv = bias[o];
            float* orow = out + ((size_t)(batch * OUT_CH + o) * T_LEN) + t0 + wt + lm;
#pragma unroll
            for (int b = 0; b < 4; ++b)
                orow[b * 16] = acc[a][b][r] + bv;
        }
    }
}

extern "C" void kernel_launch(void* const* d_in, const int* in_sizes, int n_in,
                              void* d_out, int out_size, void* d_ws, size_t ws_size,
                              hipStream_t stream) {
    const float* x      = (const float*)d_in[0];
    const float* weight = (const float*)d_in[1];
    const float* P      = (const float*)d_in[2];
    const float* bias   = (const float*)d_in[3];
    float*       out    = (float*)d_out;
    unsigned short* kern_f = (unsigned short*)d_ws;   // 256*256*33 bf16 = 4.33MB

    hipLaunchKernelGGL(build_kern,
                       dim3((OUT_CH * IN_CH + 255) / 256), dim3(256), 0, stream,
                       weight, P, kern_f);

    // block tile 128o x 128t; grid (t, o, batch) = (16, 2, 8) = 256 blocks
    dim3 grid(T_LEN / TT, OUT_CH / 128, N_BATCH);
    hipLaunchKernelGGL(dcls_conv, grid, dim3(256), 0, stream,
                       x, kern_f, bias, out);
}

// Round 13
// 161.696 us; speedup vs baseline: 1.3804x; 1.3804x over previous
//
#include <hip/hip_runtime.h>
#include <math.h>

#define N_BATCH 8
#define IN_CH   256
#define OUT_CH  256
#define T_LEN   2048
#define DKS     33
#define PAD     16
#define KC      16

// conv tiling: block 128o x 128t, 8 waves (512 thr).
// Waves 0-3: quadrants (2x2) of the output tile over i-chunks 0..3+r.
// Waves 4-7: same quadrants over i-chunks 4..7 (split-K x2) -> LDS reduce.
// Wave tile 64o x 64t: 16 MFMA per d-phase, reads/MFMA = 0.5.
#define TT 128
#define XS_STRIDE 40   // Xs row stride in bf16 elements (80B, 16B-aligned)

typedef __attribute__((ext_vector_type(8))) short bf16x8;
typedef __attribute__((ext_vector_type(4))) float f32x4;

typedef const __attribute__((address_space(1))) unsigned int glb_uint;
typedef __attribute__((address_space(3))) unsigned int lds_uint;

__device__ __forceinline__ unsigned short f2bf(float f) {
    unsigned u = __builtin_bit_cast(unsigned, f);
    unsigned r = (u + 0x7FFFu + ((u >> 16) & 1u)) >> 16;   // RNE
    return (unsigned short)r;
}

// ---------------------------------------------------------------------------
// Kernel 1: construct dense conv kernel in bf16, fragment-ready layout:
//   element (o,i,d) lives at
//   ((g*8 + c)*33 + d)*2048 + a*512 + l*8 + j
//   where g=o>>6, a=(o>>4)&3, m=o&15, c=i>>5, i_local=i&31,
//         quad=i_local>>3, j=i_local&7, l=quad*16+m.
// GATHER formulation (no runtime-indexed array -> no scratch).
// Faithful reference semantics: frac from out-channel 0; second tap dropped
// when p1+1 == 33 (d-1 <= 31 never matches).
// ---------------------------------------------------------------------------
__global__ void build_kern(const float* __restrict__ weight,
                           const float* __restrict__ P,
                           unsigned short* __restrict__ kern_f) {
    int idx = blockIdx.x * blockDim.x + threadIdx.x;   // o*IN_CH + i
    if (idx >= OUT_CH * IN_CH) return;
    int o = idx / IN_CH;
    int i = idx % IN_CH;

    const float* Po = P      + (size_t)(o * IN_CH + i) * KC;
    const float* P0 = P      + (size_t)i * KC;           // out-channel 0
    const float* Wo = weight + (size_t)(o * IN_CH + i) * KC;

    int   p1[KC];
    float w1[KC], w2[KC];
#pragma unroll
    for (int k = 0; k < KC; ++k) {
        float pp = Po[k] + (float)(DKS / 2);
        float p0 = P0[k] + (float)(DKS / 2);
        float fr = p0 - floorf(p0);
        float w  = Wo[k];
        p1[k] = (int)floorf(pp);
        w1[k] = w * (1.0f - fr);
        w2[k] = w * fr;
    }

    int g  = o >> 6;
    int ai = (o >> 4) & 3;
    int m  = o & 15;
    int c  = i >> 5;
    int il = i & 31;
    int q  = il >> 3;
    int j  = il & 7;
    size_t base = ((size_t)(g * 8 + c) * 33) * 2048
                + (size_t)ai * 512 + (size_t)(q * 16 + m) * 8 + j;

#pragma unroll
    for (int d = 0; d < DKS; ++d) {
        float acc = 0.0f;
#pragma unroll
        for (int k = 0; k < KC; ++k) {
            acc += (p1[k] == d)     ? w1[k] : 0.0f;
            acc += (p1[k] == d - 1) ? w2[k] : 0.0f;
        }
        kern_f[base + (size_t)d * 2048] = f2bf(acc);
    }
}

// ---------------------------------------------------------------------------
// Kernel 2: implicit-GEMM conv with MFMA 16x16x32 bf16.
// Synthesis of r11/r12 lessons:
//  (a) 64x64 wave tiles: reads/MFMA=0.5 (r12: conflict counter halved)
//  (b) counted-vmcnt gload_lds A-pipeline (r11: only proven +lever)
//  (c) 2 waves/SIMD via split-K x2 (r12 lesson: 1 wave/SIMD exposes all
//      latency; 64x64 tiles only give 1024 tiles -> need split-K)
// 8 waves: wave w -> quadrant q=w&3 (qo=q>>1, qt=q&1), K-group kg=w>>2
// (chunks kg*4+r, r=0..3). Xs per K-group (2 x 12.8KB); Abuf 4 bufs x 16KB
// (both K-groups' A d-slabs). Sync per r12's proven discipline:
// STAGE(p+2); VMW(4); BAR; PHASE(p) - wait BEFORE barrier, never 0 mid-loop.
// Epilogue: waves 4-7 dump acc to LDS (reuse Abuf), waves 0-3 add + bias.
// ---------------------------------------------------------------------------
__global__ __launch_bounds__(512, 2) void dcls_conv(
    const float* __restrict__ x,
    const unsigned short* __restrict__ kern_f,
    const float* __restrict__ bias,
    float* __restrict__ out)
{
    __shared__ unsigned short Xs[2][(TT + 2 * PAD) * XS_STRIDE];     // 25.6 KB
    __shared__ __align__(16) unsigned short Abuf[4][2][2][4][512];   // 64 KB

    const int t0    = blockIdx.x * TT;        // t-block (16)
    const int o0    = blockIdx.y * 128;       // o-block (2)
    const int batch = blockIdx.z;

    const int tid  = threadIdx.x;
    const int w    = tid >> 6;        // wave id 0..7
    const int l    = tid & 63;
    const int quad = l >> 4;
    const int lm   = l & 15;
    const int kg   = w >> 2;          // K-group 0..1
    const int q    = w & 3;           // quadrant 0..3
    const int qo   = q >> 1;          // o-half
    const int wt   = (q & 1) * 64;    // t-base (local)

    // staging share: wave stages rows flat = w*2+{0,1} of the 16x512 d-slab
    // flat -> kg_s = flat>>3 (== kg), g_s = (flat>>2)&1, a_s = flat&3
    const int sg  = (w >> 1) & 1;
    const int sa0 = (w & 1) * 2;

    f32x4 acc[4][4];
#pragma unroll
    for (int a = 0; a < 4; ++a)
#pragma unroll
        for (int b = 0; b < 4; ++b) acc[a][b] = (f32x4){0.f, 0.f, 0.f, 0.f};

#define VMW(N) asm volatile("s_waitcnt vmcnt(" #N ")" ::: "memory")
#define BAR()  asm volatile("s_barrier" ::: "memory")

    // stage this wave's 2x1KB share of d-slab D into Abuf[NB]
#define STAGE_A(D, NB)                                                        \
    do {                                                                      \
        _Pragma("unroll")                                                     \
        for (int j_ = 0; j_ < 2; ++j_) {                                      \
            const unsigned short* s_ = kern_f + kwb                           \
                + (size_t)(D) * 2048 + (size_t)(sa0 + j_) * 512               \
                + (size_t)l * 8;                                              \
            __builtin_amdgcn_global_load_lds((glb_uint*)s_,                   \
                (lds_uint*)&Abuf[NB][kg][sg][sa0 + j_][0], 16, 0, 0);         \
        }                                                                     \
    } while (0)

    // one phase: 4 A-frags (own o-half, own kg) + 4 B-frags, 16 MFMA
#define PHASE_BODY(NB, D)                                                     \
    do {                                                                      \
        bf16x8 afr[4], bfr[4];                                                \
        _Pragma("unroll")                                                     \
        for (int a = 0; a < 4; ++a)                                           \
            afr[a] = *(const bf16x8*)(&Abuf[NB][kg][qo][a][(size_t)l * 8]);   \
        _Pragma("unroll")                                                     \
        for (int b = 0; b < 4; ++b)                                           \
            bfr[b] = *(const bf16x8*)(&Xs[kg][(wt + b * 16 + lm + (D)) * XS_STRIDE + quad * 8]); \
        __builtin_amdgcn_s_setprio(1);                                        \
        _Pragma("unroll")                                                     \
        for (int a = 0; a < 4; ++a)                                           \
            _Pragma("unroll")                                                 \
            for (int b = 0; b < 4; ++b)                                       \
                acc[a][b] = __builtin_amdgcn_mfma_f32_16x16x32_bf16(          \
                    afr[a], bfr[b], acc[a][b], 0, 0, 0);                      \
        __builtin_amdgcn_s_setprio(0);                                        \
    } while (0)

    for (int r = 0; r < 4; ++r) {
        __syncthreads();   // prev round's Xs/Abuf reads done; vmcnt drained

        // per-wave kern base: group g = by*2+sg, chunk = kg*4+r
        const size_t kwb =
            ((size_t)((blockIdx.y * 2 + sg) * 8 + kg * 4 + r) * 33) * 2048;

        // prologue: 2-deep A prefetch (d=0,1 -> bufs 0,1)
        STAGE_A(0, 0);
        STAGE_A(1, 1);

        // ---- stage Xs for both K-groups: 2 x (32 i x 160 t) ----
#pragma unroll
        for (int it = 0; it < 10; ++it) {
            int idx = tid + it * 512;          // 0..5119
            int kgs = idx / 2560;              // which K-group
            int rem = idx - kgs * 2560;
            int ip  = rem / 160;               // i-pair 0..15
            int t   = rem - ip * 160;          // 0..159
            int gg  = t0 - PAD + t;
            float v0 = 0.f, v1 = 0.f;
            if ((unsigned)gg < (unsigned)T_LEN) {
                const float* xb = x
                    + ((size_t)(batch * IN_CH + (kgs * 4 + r) * 32 + ip * 2) * T_LEN) + gg;
                v0 = xb[0];
                v1 = xb[T_LEN];
            }
            unsigned pk = (unsigned)f2bf(v0) | ((unsigned)f2bf(v1) << 16);
            *(unsigned*)(&Xs[kgs][t * XS_STRIDE + ip * 2]) = pk;
        }
        __syncthreads();   // Xs ready; prologue A-stages landed (full drain)

        // ---- 33 d-phases, counted-vmcnt pipeline (never 0 mid-loop) ----
        for (int p = 0; p < 31; ++p) {
            STAGE_A(p + 2, (p + 2) & 3);   // stage phase p+2 (2 loads)
            VMW(4);    // phase p's 2 loads landed; 4 newer in flight
            BAR();     // all waves arrived => full buf[p&3] resident
            PHASE_BODY(p & 3, p);
        }
        VMW(2); BAR(); PHASE_BODY(3, 31);   // p=31
        VMW(0); BAR(); PHASE_BODY(0, 32);   // p=32
    }
#undef STAGE_A
#undef PHASE_BODY
#undef VMW
#undef BAR

    // ---- split-K reduce (reuse Abuf as 4 x 64x64 f32 tiles) + epilogue ----
    __syncthreads();
    float* red = (float*)Abuf;
    if (w >= 4) {
#pragma unroll
        for (int a = 0; a < 4; ++a)
#pragma unroll
            for (int b = 0; b < 4; ++b)
#pragma unroll
                for (int r2 = 0; r2 < 4; ++r2)
                    red[q * 4096 + (a * 16 + quad * 4 + r2) * 64 + b * 16 + lm]
                        = acc[a][b][r2];
    }
    __syncthreads();
    if (w < 4) {
#pragma unroll
        for (int a = 0; a < 4; ++a) {
#pragma unroll
            for (int r2 = 0; r2 < 4; ++r2) {
                int o = o0 + qo * 64 + a * 16 + quad * 4 + r2;
                float bv = bias[o];
                float* orow = out + ((size_t)(batch * OUT_CH + o) * T_LEN) + t0 + wt + lm;
#pragma unroll
                for (int b = 0; b < 4; ++b)
                    orow[b * 16] = acc[a][b][r2]
                        + red[q * 4096 + (a * 16 + quad * 4 + r2) * 64 + b * 16 + lm]
                        + bv;
            }
        }
    }
}

extern "C" void kernel_launch(void* const* d_in, const int* in_sizes, int n_in,
                              void* d_out, int out_size, void* d_ws, size_t ws_size,
                              hipStream_t stream) {
    const float* x      = (const float*)d_in[0];
    const float* weight = (const float*)d_in[1];
    const float* P      = (const float*)d_in[2];
    const float* bias   = (const float*)d_in[3];
    float*       out    = (float*)d_out;
    unsigned short* kern_f = (unsigned short*)d_ws;   // 256*256*33 bf16 = 4.33MB

    hipLaunchKernelGGL(build_kern,
                       dim3((OUT_CH * IN_CH + 255) / 256), dim3(256), 0, stream,
                       weight, P, kern_f);

    // block tile 128o x 128t, 8 waves, split-K x2
    dim3 grid(T_LEN / TT, OUT_CH / 128, N_BATCH);
    hipLaunchKernelGGL(dcls_conv, grid, dim3(512), 0, stream,
                       x, kern_f, bias, out);
}

// Round 14
// 152.055 us; speedup vs baseline: 1.4679x; 1.0634x over previous
//
#include <hip/hip_runtime.h>
#include <math.h>

#define N_BATCH 8
#define IN_CH   256
#define OUT_CH  256
#define T_LEN   2048
#define DKS     33
#define PAD     16
#define KC      16

// conv tiling: block 128o x 128t, 8 waves (512 thr), split-K x2.
// Wave w: K-group kg=w>>2 (chunks kg*4+r), quadrant q=w&3 (qo=q>>1, t=(q&1)*64).
// Wave tile 64o x 64t. d-PAIR phases (17/round) with counted-vmcnt pipeline.
#define TT 128
#define XS_STRIDE 40   // bf16 elems/row (80B, 16B-aligned)

typedef __attribute__((ext_vector_type(8))) short bf16x8;
typedef __attribute__((ext_vector_type(4))) float f32x4;

typedef const __attribute__((address_space(1))) unsigned int glb_uint;
typedef __attribute__((address_space(3))) unsigned int lds_uint;

__device__ __forceinline__ unsigned short f2bf(float f) {
    unsigned u = __builtin_bit_cast(unsigned, f);
    unsigned r = (u + 0x7FFFu + ((u >> 16) & 1u)) >> 16;   // RNE
    return (unsigned short)r;
}

// ---------------------------------------------------------------------------
// Kernel 1: construct dense conv kernel in bf16, fragment-ready layout:
//   element (o,i,d) at ((g*8 + c)*33 + d)*2048 + a*512 + (q*16+m)*8 + j
//   (g=o>>6, a=(o>>4)&3, m=o&15, c=i>>5, q=(i&31)>>3, j=i&7).
// GATHER formulation (no runtime-indexed array -> no scratch). Faithful
// semantics: frac from out-channel 0; second tap dropped when p1+1 == 33.
// ---------------------------------------------------------------------------
__global__ void build_kern(const float* __restrict__ weight,
                           const float* __restrict__ P,
                           unsigned short* __restrict__ kern_f) {
    int idx = blockIdx.x * blockDim.x + threadIdx.x;   // o*IN_CH + i
    if (idx >= OUT_CH * IN_CH) return;
    int o = idx / IN_CH;
    int i = idx % IN_CH;

    const float* Po = P      + (size_t)(o * IN_CH + i) * KC;
    const float* P0 = P      + (size_t)i * KC;           // out-channel 0
    const float* Wo = weight + (size_t)(o * IN_CH + i) * KC;

    int   p1[KC];
    float w1[KC], w2[KC];
#pragma unroll
    for (int k = 0; k < KC; ++k) {
        float pp = Po[k] + (float)(DKS / 2);
        float p0 = P0[k] + (float)(DKS / 2);
        float fr = p0 - floorf(p0);
        float w  = Wo[k];
        p1[k] = (int)floorf(pp);
        w1[k] = w * (1.0f - fr);
        w2[k] = w * fr;
    }

    int g  = o >> 6;
    int ai = (o >> 4) & 3;
    int m  = o & 15;
    int c  = i >> 5;
    int il = i & 31;
    int q  = il >> 3;
    int j  = il & 7;
    size_t base = ((size_t)(g * 8 + c) * 33) * 2048
                + (size_t)ai * 512 + (size_t)(q * 16 + m) * 8 + j;

#pragma unroll
    for (int d = 0; d < DKS; ++d) {
        float acc = 0.0f;
#pragma unroll
        for (int k = 0; k < KC; ++k) {
            acc += (p1[k] == d)     ? w1[k] : 0.0f;
            acc += (p1[k] == d - 1) ? w2[k] : 0.0f;
        }
        kern_f[base + (size_t)d * 2048] = f2bf(acc);
    }
}

// ---------------------------------------------------------------------------
// Kernel 2 (r13 geometry + r14 schedule):
//  - d-PAIR phases: 17/round instead of 33 -> half the barriers/VMWs; fully
//    unrolled so all addresses are compile-time (r13: 258cy/phase VALU).
//  - Abuf 3 bufs x 32KB (d-pair slabs), depth-1 stage, VMW(4) steady, never
//    0 mid-loop. Rewrite of buf b issued one barrier after its last read.
//  - T14 async Xs: round r+1's 20 x-loads issued mid-round (clamped addr,
//    unconditional -> uniform vmcnt count); iter8 VMW(24) keeps them in
//    flight (r<3 only); LDS write at round end behind lgkmcnt-fenced BAR.
// ---------------------------------------------------------------------------
__global__ __launch_bounds__(512, 2) void dcls_conv(
    const float* __restrict__ x,
    const unsigned short* __restrict__ kern_f,
    const float* __restrict__ bias,
    float* __restrict__ out)
{
    __shared__ unsigned short Xs[2][(TT + 2 * PAD) * XS_STRIDE];        // [kg] 25.6 KB
    __shared__ __align__(16) unsigned short Abuf[3][2][2][2][4][512];   // [buf][dd][kg][g][a] 96 KB

    const int t0    = blockIdx.x * TT;
    const int o0    = blockIdx.y * 128;
    const int batch = blockIdx.z;

    const int tid  = threadIdx.x;
    const int w    = tid >> 6;        // wave 0..7
    const int l    = tid & 63;
    const int quad = l >> 4;
    const int lm   = l & 15;
    const int kg   = w >> 2;          // K-group
    const int q    = w & 3;           // quadrant
    const int qo   = q >> 1;          // o-half
    const int wt   = (q & 1) * 64;    // t-base

    const int sg  = (w >> 1) & 1;     // staging: g-half
    const int sa0 = (w & 1) * 2;      // staging: a-row pair

    float xv0[10], xv1[10];

    f32x4 acc[4][4];
#pragma unroll
    for (int a = 0; a < 4; ++a)
#pragma unroll
        for (int b = 0; b < 4; ++b) acc[a][b] = (f32x4){0.f, 0.f, 0.f, 0.f};

#define KWB(R) (((size_t)((blockIdx.y * 2 + sg) * 8 + kg * 4 + (R)) * 33) * 2048)

#define VMW(N)  asm volatile("s_waitcnt vmcnt(" #N ")" ::: "memory")
#define LGKM0() asm volatile("s_waitcnt lgkmcnt(0)" ::: "memory")
#define BAR()   asm volatile("s_barrier" ::: "memory")

    // load round R's x-tile into regs (clamped addr, unconditional: every
    // wave issues exactly 20 vmcnt events -> VMW counts stay exact)
#define XLOAD(R)                                                              \
    do {                                                                      \
        const int rr_ = (R);                                                  \
        _Pragma("unroll")                                                     \
        for (int it = 0; it < 10; ++it) {                                     \
            int idx = tid + it * 512;                                         \
            int kgs = idx / 2560;                                             \
            int rem = idx - kgs * 2560;                                       \
            int ip  = rem / 160;                                              \
            int t   = rem - ip * 160;                                         \
            int gg  = t0 - PAD + t;                                           \
            int ggc = gg < 0 ? 0 : (gg > T_LEN - 1 ? T_LEN - 1 : gg);         \
            const float* xb = x + ((size_t)(batch * IN_CH                     \
                                 + (kgs * 4 + rr_) * 32 + ip * 2) * T_LEN) + ggc; \
            float a_ = xb[0], b_ = xb[T_LEN];                                 \
            bool ok = (unsigned)gg < (unsigned)T_LEN;                         \
            xv0[it] = ok ? a_ : 0.f;                                          \
            xv1[it] = ok ? b_ : 0.f;                                          \
        }                                                                     \
    } while (0)

#define XWRITE()                                                              \
    do {                                                                      \
        _Pragma("unroll")                                                     \
        for (int it = 0; it < 10; ++it) {                                     \
            int idx = tid + it * 512;                                         \
            int kgs = idx / 2560;                                             \
            int rem = idx - kgs * 2560;                                       \
            int ip  = rem / 160;                                              \
            int t   = rem - ip * 160;                                         \
            unsigned pk = (unsigned)f2bf(xv0[it])                             \
                        | ((unsigned)f2bf(xv1[it]) << 16);                    \
            *(unsigned*)(&Xs[kgs][t * XS_STRIDE + ip * 2]) = pk;              \
        }                                                                     \
    } while (0)

    // stage d-pair PAIR (d = 2*PAIR, 2*PAIR+1) into Abuf[NB]: 4 loads/wave
#define STAGE_PAIR(PAIR, NB, KW)                                              \
    do {                                                                      \
        _Pragma("unroll")                                                     \
        for (int dd_ = 0; dd_ < 2; ++dd_) {                                   \
            _Pragma("unroll")                                                 \
            for (int j_ = 0; j_ < 2; ++j_) {                                  \
                const unsigned short* s_ = kern_f + (KW)                      \
                    + (size_t)((PAIR) * 2 + dd_) * 2048                       \
                    + (size_t)(sa0 + j_) * 512 + (size_t)l * 8;               \
                __builtin_amdgcn_global_load_lds((glb_uint*)s_,               \
                    (lds_uint*)&Abuf[(NB)][dd_][kg][sg][sa0 + j_][0], 16, 0, 0); \
            }                                                                 \
        }                                                                     \
    } while (0)

    // stage the odd d=32 half-slab into Abuf[NB][0]: 2 loads/wave
#define STAGE_HALF(NB, KW)                                                    \
    do {                                                                      \
        _Pragma("unroll")                                                     \
        for (int j_ = 0; j_ < 2; ++j_) {                                      \
            const unsigned short* s_ = kern_f + (KW)                          \
                + (size_t)32 * 2048 + (size_t)(sa0 + j_) * 512                \
                + (size_t)l * 8;                                              \
            __builtin_amdgcn_global_load_lds((glb_uint*)s_,                   \
                (lds_uint*)&Abuf[(NB)][0][kg][sg][sa0 + j_][0], 16, 0, 0);    \
        }                                                                     \
    } while (0)

    // one d: 4 A + 4 B reads, 16 MFMA
#define PHASE_D(NB, DD, D)                                                    \
    do {                                                                      \
        bf16x8 afr[4], bfr[4];                                                \
        _Pragma("unroll")                                                     \
        for (int a = 0; a < 4; ++a)                                           \
            afr[a] = *(const bf16x8*)(&Abuf[(NB)][DD][kg][qo][a][(size_t)l * 8]); \
        _Pragma("unroll")                                                     \
        for (int b = 0; b < 4; ++b)                                           \
            bfr[b] = *(const bf16x8*)(&Xs[kg][(wt + b * 16 + lm + (D)) * XS_STRIDE + quad * 8]); \
        __builtin_amdgcn_s_setprio(1);                                        \
        _Pragma("unroll")                                                     \
        for (int a = 0; a < 4; ++a)                                           \
            _Pragma("unroll")                                                 \
            for (int b = 0; b < 4; ++b)                                       \
                acc[a][b] = __builtin_amdgcn_mfma_f32_16x16x32_bf16(          \
                    afr[a], bfr[b], acc[a][b], 0, 0, 0);                      \
        __builtin_amdgcn_s_setprio(0);                                        \
    } while (0)

#define PHASE_PAIR(NB, D0) do { PHASE_D(NB, 0, D0); PHASE_D(NB, 1, (D0) + 1); } while (0)

    // ---- cold prologue ----
    XLOAD(0);
    STAGE_PAIR(0, 0, KWB(0));
    XWRITE();
    __syncthreads();   // Xs visible; prologue stage drained (cold, once)

    for (int r = 0; r < 4; ++r) {
        const size_t kwb = KWB(r);

        // pairs 0..7 (stage pair p+1 -> buf (p+1)%3, depth-1, VMW(4))
#pragma unroll
        for (int p = 0; p < 8; ++p) {
            STAGE_PAIR(p + 1, (p + 1) % 3, kwb);
            VMW(4);
            BAR();
            PHASE_PAIR(p % 3, 2 * p);
        }

        // iter 8: if next round exists, its x-loads go in flight here;
        // VMW(24) = 4 (stage pair9) + 20 (x-loads) kept outstanding.
        if (r < 3) {
            XLOAD(r + 1);
            STAGE_PAIR(9, 0, kwb);
            VMW(24);
            BAR();
            PHASE_PAIR(2, 16);
        } else {
            STAGE_PAIR(9, 0, kwb);
            VMW(4);
            BAR();
            PHASE_PAIR(2, 16);
        }

        // pairs 9..14
#pragma unroll
        for (int p = 9; p < 15; ++p) {
            STAGE_PAIR(p + 1, (p + 1) % 3, kwb);
            VMW(4);
            BAR();
            PHASE_PAIR(p % 3, 2 * p);
        }

        // iter 15: stage d=32 half into buf 1; pair15 in buf 0
        STAGE_HALF(1, kwb);
        VMW(2);
        BAR();
        PHASE_PAIR(0, 30);

        // iter 16: d=32 tail from buf 1
        VMW(0);
        BAR();
        PHASE_D(1, 0, 32);

        if (r < 3) {
            BAR();                          // all waves done all reads
            STAGE_PAIR(0, 0, KWB(r + 1));   // next round's prologue (buf 0)
            XWRITE();                       // next round's Xs (regs loaded @iter8)
            LGKM0();                        // ds_writes visible
            BAR();
        }
    }
#undef XLOAD
#undef XWRITE
#undef STAGE_PAIR
#undef STAGE_HALF
#undef PHASE_D
#undef PHASE_PAIR
#undef VMW
#undef LGKM0
#undef BAR
#undef KWB

    // ---- split-K reduce (reuse Abuf as 4 x 64x64 f32 tiles) + epilogue ----
    __syncthreads();
    float* red = (float*)Abuf;
    if (w >= 4) {
#pragma unroll
        for (int a = 0; a < 4; ++a)
#pragma unroll
            for (int b = 0; b < 4; ++b)
#pragma unroll
                for (int r2 = 0; r2 < 4; ++r2)
                    red[q * 4096 + (a * 16 + quad * 4 + r2) * 64 + b * 16 + lm]
                        = acc[a][b][r2];
    }
    __syncthreads();
    if (w < 4) {
#pragma unroll
        for (int a = 0; a < 4; ++a) {
#pragma unroll
            for (int r2 = 0; r2 < 4; ++r2) {
                int o = o0 + qo * 64 + a * 16 + quad * 4 + r2;
                float bv = bias[o];
                float* orow = out + ((size_t)(batch * OUT_CH + o) * T_LEN) + t0 + wt + lm;
#pragma unroll
                for (int b = 0; b < 4; ++b)
                    orow[b * 16] = acc[a][b][r2]
                        + red[q * 4096 + (a * 16 + quad * 4 + r2) * 64 + b * 16 + lm]
                        + bv;
            }
        }
    }
}

extern "C" void kernel_launch(void* const* d_in, const int* in_sizes, int n_in,
                              void* d_out, int out_size, void* d_ws, size_t ws_size,
                              hipStream_t stream) {
    const float* x      = (const float*)d_in[0];
    const float* weight = (const float*)d_in[1];
    const float* P      = (const float*)d_in[2];
    const float* bias   = (const float*)d_in[3];
    float*       out    = (float*)d_out;
    unsigned short* kern_f = (unsigned short*)d_ws;   // 256*256*33 bf16 = 4.33MB

    hipLaunchKernelGGL(build_kern,
                       dim3((OUT_CH * IN_CH + 255) / 256), dim3(256), 0, stream,
                       weight, P, kern_f);

    dim3 grid(T_LEN / TT, OUT_CH / 128, N_BATCH);
    hipLaunchKernelGGL(dcls_conv, grid, dim3(512), 0, stream,
                       x, kern_f, bias, out);
}

// Round 16
// 127.987 us; speedup vs baseline: 1.7439x; 1.1880x over previous
//
#include <hip/hip_runtime.h>
#include <math.h>

#define N_BATCH 8
#define IN_CH   256
#define OUT_CH  256
#define T_LEN   2048
#define DKS     33
#define PAD     16
#define KC      16

// conv tiling: block 128o x 128t, 8 waves (512 thr), split-K x2.
// Wave w: K-group kg=w>>2 (chunks kg*4+r), quadrant q=w&3 (qo=q>>1, t=(q&1)*64).
// Wave tile 64o x 64t. A-frags: global->REGISTER prefetch (depth 2, 3-buf
// rotation, compile-time indices). B from LDS Xs. NO per-phase barriers.
#define TT 128
#define XS_STRIDE 40   // bf16 elems/row (80B, 16B-aligned)

typedef __attribute__((ext_vector_type(8))) short bf16x8;
typedef __attribute__((ext_vector_type(4))) float f32x4;

__device__ __forceinline__ unsigned short f2bf(float f) {
    unsigned u = __builtin_bit_cast(unsigned, f);
    unsigned r = (u + 0x7FFFu + ((u >> 16) & 1u)) >> 16;   // RNE
    return (unsigned short)r;
}

// ---------------------------------------------------------------------------
// Kernel 1: construct dense conv kernel in bf16, fragment-ready layout:
//   element (o,i,d) at ((g*8 + c)*33 + d)*2048 + a*512 + (q*16+m)*8 + j
//   (g=o>>6, a=(o>>4)&3, m=o&15, c=i>>5, q=(i&31)>>3, j=i&7).
// GATHER formulation (no runtime-indexed array -> no scratch). Faithful
// semantics: frac from out-channel 0; second tap dropped when p1+1 == 33.
// ---------------------------------------------------------------------------
__global__ void build_kern(const float* __restrict__ weight,
                           const float* __restrict__ P,
                           unsigned short* __restrict__ kern_f) {
    int idx = blockIdx.x * blockDim.x + threadIdx.x;   // o*IN_CH + i
    if (idx >= OUT_CH * IN_CH) return;
    int o = idx / IN_CH;
    int i = idx % IN_CH;

    const float* Po = P      + (size_t)(o * IN_CH + i) * KC;
    const float* P0 = P      + (size_t)i * KC;           // out-channel 0
    const float* Wo = weight + (size_t)(o * IN_CH + i) * KC;

    int   p1[KC];
    float w1[KC], w2[KC];
#pragma unroll
    for (int k = 0; k < KC; ++k) {
        float pp = Po[k] + (float)(DKS / 2);
        float p0 = P0[k] + (float)(DKS / 2);
        float fr = p0 - floorf(p0);
        float w  = Wo[k];
        p1[k] = (int)floorf(pp);
        w1[k] = w * (1.0f - fr);
        w2[k] = w * fr;
    }

    int g  = o >> 6;
    int ai = (o >> 4) & 3;
    int m  = o & 15;
    int c  = i >> 5;
    int il = i & 31;
    int q  = il >> 3;
    int j  = il & 7;
    size_t base = ((size_t)(g * 8 + c) * 33) * 2048
                + (size_t)ai * 512 + (size_t)(q * 16 + m) * 8 + j;

#pragma unroll
    for (int d = 0; d < DKS; ++d) {
        float acc = 0.0f;
#pragma unroll
        for (int k = 0; k < KC; ++k) {
            acc += (p1[k] == d)     ? w1[k] : 0.0f;
            acc += (p1[k] == d - 1) ? w2[k] : 0.0f;
        }
        kern_f[base + (size_t)d * 2048] = f2bf(acc);
    }
}

// ---------------------------------------------------------------------------
// Kernel 2 (r14 post-mortem): A-frags moved LDS -> registers.
//  - r14's Abuf existed to amortize the global A-path; with 64x64 tiles a
//    wave needs only 4 coalesced dwordx4 loads per d -> prefetch to regs,
//    depth 2 (3-buffer rotation, d%3 compile-time via full d-unroll).
//  - LDS reads halve (B only): ~50K cy/CU (26%) - LDS off the critical path.
//  - A in registers is wave-private -> NO per-phase barriers (68 -> 8 total);
//    no inline-asm vmcnt needed, register deps are compiler-tracked.
//  - Xs for round r+1: reg-load issued mid-round (d==16), LDS write behind
//    the round-end barrier (T14).
// ---------------------------------------------------------------------------
__global__ __launch_bounds__(512, 2) void dcls_conv(
    const float* __restrict__ x,
    const unsigned short* __restrict__ kern_f,
    const float* __restrict__ bias,
    float* __restrict__ out)
{
    __shared__ __align__(16) unsigned char smem[65536];   // Xs[2][160*40] u16 (25.6KB) / reduce 64KB
    unsigned short* XsB = (unsigned short*)smem;

    const int t0    = blockIdx.x * TT;
    const int o0    = blockIdx.y * 128;
    const int batch = blockIdx.z;

    const int tid  = threadIdx.x;
    const int w    = tid >> 6;        // wave 0..7
    const int l    = tid & 63;
    const int quad = l >> 4;
    const int lm   = l & 15;
    const int kg   = w >> 2;          // K-group
    const int q    = w & 3;           // quadrant
    const int qo   = q >> 1;          // o-half
    const int wt   = (q & 1) * 64;    // t-base

    float xv0[10], xv1[10];
    bf16x8 apre[3][4];                // 3-deep rotating A prefetch

    f32x4 acc[4][4];
#pragma unroll
    for (int a = 0; a < 4; ++a)
#pragma unroll
        for (int b = 0; b < 4; ++b) acc[a][b] = (f32x4){0.f, 0.f, 0.f, 0.f};

    // load round R's x-tile into regs (clamped addr, branch-free)
#define XLOAD(R)                                                              \
    do {                                                                      \
        const int rr_ = (R);                                                  \
        _Pragma("unroll")                                                     \
        for (int it = 0; it < 10; ++it) {                                     \
            int idx = tid + it * 512;                                         \
            int kgs = idx / 2560;                                             \
            int rem = idx - kgs * 2560;                                       \
            int ip  = rem / 160;                                              \
            int t   = rem - ip * 160;                                         \
            int gg  = t0 - PAD + t;                                           \
            int ggc = gg < 0 ? 0 : (gg > T_LEN - 1 ? T_LEN - 1 : gg);         \
            const float* xb = x + ((size_t)(batch * IN_CH                     \
                                 + (kgs * 4 + rr_) * 32 + ip * 2) * T_LEN) + ggc; \
            float a_ = xb[0], b_ = xb[T_LEN];                                 \
            bool ok = (unsigned)gg < (unsigned)T_LEN;                         \
            xv0[it] = ok ? a_ : 0.f;                                          \
            xv1[it] = ok ? b_ : 0.f;                                          \
        }                                                                     \
    } while (0)

#define XWRITE()                                                              \
    do {                                                                      \
        _Pragma("unroll")                                                     \
        for (int it = 0; it < 10; ++it) {                                     \
            int idx = tid + it * 512;                                         \
            int kgs = idx / 2560;                                             \
            int rem = idx - kgs * 2560;                                       \
            int ip  = rem / 160;                                              \
            int t   = rem - ip * 160;                                         \
            unsigned pk = (unsigned)f2bf(xv0[it])                             \
                        | ((unsigned)f2bf(xv1[it]) << 16);                    \
            *(unsigned*)(&XsB[kgs * 6400 + t * XS_STRIDE + ip * 2]) = pk;     \
        }                                                                     \
    } while (0)

    // load the 4 A-frags for depth-slot D into apre[NB] (coalesced 4x1KB)
#define ALOAD(NB, D)                                                          \
    do {                                                                      \
        _Pragma("unroll")                                                     \
        for (int a = 0; a < 4; ++a)                                           \
            apre[NB][a] = *(const bf16x8*)(kab + (size_t)(D) * 2048 + a * 512); \
    } while (0)

    // one d: 4 B-reads from Xs, 16 MFMA on apre[NB]
#define PHASE(NB, D)                                                          \
    do {                                                                      \
        bf16x8 bfr[4];                                                        \
        _Pragma("unroll")                                                     \
        for (int b = 0; b < 4; ++b)                                           \
            bfr[b] = *(const bf16x8*)(&XsB[kg * 6400                          \
                + (wt + b * 16 + lm + (D)) * XS_STRIDE + quad * 8]);          \
        __builtin_amdgcn_s_setprio(1);                                        \
        _Pragma("unroll")                                                     \
        for (int a = 0; a < 4; ++a)                                           \
            _Pragma("unroll")                                                 \
            for (int b = 0; b < 4; ++b)                                       \
                acc[a][b] = __builtin_amdgcn_mfma_f32_16x16x32_bf16(          \
                    apre[NB][a], bfr[b], acc[a][b], 0, 0, 0);                 \
        __builtin_amdgcn_s_setprio(0);                                        \
    } while (0)

    // ---- prologue: round 0's Xs ----
    XLOAD(0);
    XWRITE();
    __syncthreads();

    for (int r = 0; r < 4; ++r) {
        // this wave's A base: o-group = by*2+qo, chunk = kg*4+r
        const unsigned short* kab = kern_f
            + ((size_t)((blockIdx.y * 2 + qo) * 8 + kg * 4 + r) * 33) * 2048
            + (size_t)l * 8;

        ALOAD(0, 0);
        ALOAD(1, 1);

        // ---- 33 barrier-free phases, depth-2 register A-pipeline ----
#pragma unroll
        for (int d = 0; d < 33; ++d) {
            if (d < 31) ALOAD((d + 2) % 3, d + 2);
            if (d == 16 && r < 3) XLOAD(r + 1);   // next round's x in flight
            PHASE(d % 3, d);
        }

        __syncthreads();            // all waves' Xs reads done
        if (r < 3) XWRITE();        // publish next round's Xs
        __syncthreads();
    }
#undef XLOAD
#undef XWRITE
#undef ALOAD
#undef PHASE

    // ---- split-K reduce (smem reused as 4 x 64x64 f32 tiles) + epilogue ----
    float* red = (float*)smem;
    if (w >= 4) {
#pragma unroll
        for (int a = 0; a < 4; ++a)
#pragma unroll
            for (int b = 0; b < 4; ++b)
#pragma unroll
                for (int r2 = 0; r2 < 4; ++r2)
                    red[q * 4096 + (a * 16 + quad * 4 + r2) * 64 + b * 16 + lm]
                        = acc[a][b][r2];
    }
    __syncthreads();
    if (w < 4) {
#pragma unroll
        for (int a = 0; a < 4; ++a) {
#pragma unroll
            for (int r2 = 0; r2 < 4; ++r2) {
                int o = o0 + qo * 64 + a * 16 + quad * 4 + r2;
                float bv = bias[o];
                float* orow = out + ((size_t)(batch * OUT_CH + o) * T_LEN) + t0 + wt + lm;
#pragma unroll
                for (int b = 0; b < 4; ++b)
                    orow[b * 16] = acc[a][b][r2]
                        + red[q * 4096 + (a * 16 + quad * 4 + r2) * 64 + b * 16 + lm]
                        + bv;
            }
        }
    }
}

extern "C" void kernel_launch(void* const* d_in, const int* in_sizes, int n_in,
                              void* d_out, int out_size, void* d_ws, size_t ws_size,
                              hipStream_t stream) {
    const float* x      = (const float*)d_in[0];
    const float* weight = (const float*)d_in[1];
    const float* P      = (const float*)d_in[2];
    const float* bias   = (const float*)d_in[3];
    float*       out    = (float*)d_out;
    unsigned short* kern_f = (unsigned short*)d_ws;   // 256*256*33 bf16 = 4.33MB

    hipLaunchKernelGGL(build_kern,
                       dim3((OUT_CH * IN_CH + 255) / 256), dim3(256), 0, stream,
                       weight, P, kern_f);

    dim3 grid(T_LEN / TT, OUT_CH / 128, N_BATCH);
    hipLaunchKernelGGL(dcls_conv, grid, dim3(512), 0, stream,
                       x, kern_f, bias, out);
}